// Round 8
// baseline (354.478 us; speedup 1.0000x reference)
//
#include <hip/hip_runtime.h>
#include <math.h>

#define NNODES 50000
#define NEG_SLOPE 0.2f
#define NB 391       // ceil(50000/128) buckets
#define BW 128       // nodes per bucket
#define CHUNK 4096   // edges per block in bin_scatter
#define CAP 8128     // arena slots per bucket in tmp (mean 4224, sigma ~64)

typedef __bf16 bf16x8 __attribute__((ext_vector_type(8)));
typedef float f32x4 __attribute__((ext_vector_type(4)));
typedef int i32x4 __attribute__((ext_vector_type(4)));

__device__ inline float rlane(float v, int l) {
    return __uint_as_float(__builtin_amdgcn_readlane((int)__float_as_uint(v), l));
}

// ---------------------------------------------------------------------------
// prep: W1 f32 -> bf16 panels [k/8][n][k%8]  +  bcur arena-cursor init.
// ---------------------------------------------------------------------------
__global__ void prep(const float* __restrict__ W1, __bf16* __restrict__ W1b,
                     int* __restrict__ bcur) {
    int i = blockIdx.x * 256 + threadIdx.x;
    if (i < NB) bcur[i] = i * CAP;
    else if (i == NB) bcur[NB] = 0;  // gcur (slot compaction cursor)
    if (i >= 512 * 64) return;
    int k = i >> 6, n = i & 63;
    W1b[((size_t)(k >> 3) * 64 + n) * 8 + (k & 7)] = (__bf16)W1[i];
}

// ---------------------------------------------------------------------------
// bin_scatter: per-block LDS bucket histogram -> one reservation atomic per
// bucket -> packed (dst&127)<<16|src into block-private contiguous tmp runs.
// ---------------------------------------------------------------------------
__global__ __launch_bounds__(256) void bin_scatter(const int* __restrict__ ei,
                                                   int E, int N, int* bcur,
                                                   int* __restrict__ tmp) {
    __shared__ int lcnt[NB];
    __shared__ int lbase[NB];
    int tid = threadIdx.x;
    int base0 = blockIdx.x * CHUNK;
    int lim = min(base0 + CHUNK, E + N);
    for (int i = tid; i < NB; i += 256) lcnt[i] = 0;
    __syncthreads();
    for (int e = base0 + tid; e < lim; e += 256) {
        int d = (e < E) ? ei[E + e] : e - E;  // row 1 = dst; tail = self-loops
        atomicAdd(&lcnt[d >> 7], 1);
    }
    __syncthreads();
    for (int b = tid; b < NB; b += 256) {
        int c = lcnt[b];
        lbase[b] = c ? atomicAdd(&bcur[b], c) : 0;
    }
    __syncthreads();
    for (int i = tid; i < NB; i += 256) lcnt[i] = 0;
    __syncthreads();
    for (int e = base0 + tid; e < lim; e += 256) {
        int s, d;
        if (e < E) { s = ei[e]; d = ei[E + e]; }
        else       { s = d = e - E; }
        int b = d >> 7;
        int p = atomicAdd(&lcnt[b], 1);
        tmp[lbase[b] + p] = ((d & 127) << 16) | s;  // src < 50000 < 2^16
    }
}

// ---------------------------------------------------------------------------
// csr_finalize: one block per bucket; per-node LDS count + scan; block
// reserves m compact slots from gcur; writes off/off_end and scatters slot.
// ---------------------------------------------------------------------------
__global__ __launch_bounds__(256) void csr_finalize(int* __restrict__ bcur,
                                                    const int* __restrict__ tmp,
                                                    int N, int* __restrict__ off,
                                                    int* __restrict__ off_end,
                                                    int* __restrict__ slot) {
    __shared__ int cnt[BW];
    __shared__ int cur[BW];
    __shared__ int cbase_s;
    int b = blockIdx.x, tid = threadIdx.x;
    int base = b * CAP;
    int m = bcur[b] - base;
    if (tid < BW) cnt[tid] = 0;
    __syncthreads();
    for (int i = tid; i < m; i += 256)
        atomicAdd(&cnt[(tmp[base + i] >> 16) & 127], 1);
    __syncthreads();
    if (tid == 0) cbase_s = atomicAdd(&bcur[NB], m);  // compact reservation
    int myv = (tid < BW) ? cnt[tid] : 0;
    for (int o = 1; o < BW; o <<= 1) {
        int u = 0;
        if (tid >= o && tid < BW) u = cnt[tid - o];
        __syncthreads();
        if (tid < BW) cnt[tid] += u;
        __syncthreads();
    }
    if (tid < BW) {
        int ex = cbase_s + cnt[tid] - myv;  // exclusive, compact coords
        cur[tid] = ex;
        int g = b * BW + tid;
        if (g < N) { off[g] = ex; off_end[g] = ex + myv; }
    }
    __syncthreads();
    for (int i = tid; i < m; i += 256) {
        int v = tmp[base + i];
        int k = (v >> 16) & 127;
        int p = atomicAdd(&cur[k], 1);
        slot[p] = v & 0xFFFF;
    }
}

// ---------------------------------------------------------------------------
// gemm1_mfma + fused att1 (R2-proven): H1b = bf16(X) @ bf16(W1); epilogue
// computes BOTH a_src1[n,h] and a_dst1[n,h] from the f32 accumulators.
// D-fragment: col = 16t + l15, row = quad*4 + r. h = 2t + (l15>>3).
// ---------------------------------------------------------------------------
__global__ __launch_bounds__(256) void gemm1_mfma(const float* __restrict__ X,
                                                  const __bf16* __restrict__ W1b,
                                                  const float* __restrict__ att_s1,
                                                  const float* __restrict__ att_d1,
                                                  __bf16* __restrict__ H1b,
                                                  float* __restrict__ a_s1,
                                                  float* __restrict__ a_d1,
                                                  int M) {
    __shared__ __bf16 As[2048];  // [kq 0..3][m 0..63][8]
    __shared__ __bf16 Bs[2048];  // [kq 0..3][n 0..63][8]
    int tid = threadIdx.x, wid = tid >> 6, lane = tid & 63;
    int quad = lane >> 4, l15 = lane & 15;
    int m0 = blockIdx.x * 64;
    f32x4 acc[4] = {{0.f, 0.f, 0.f, 0.f}, {0.f, 0.f, 0.f, 0.f},
                    {0.f, 0.f, 0.f, 0.f}, {0.f, 0.f, 0.f, 0.f}};
    int mrow = tid >> 2;   // 0..63 (staging role)
    int kq_w = tid & 3;    // k-chunk (staging role)
    int xrow = min(m0 + mrow, M - 1);  // clamp: garbage rows never stored
    const float* xp = X + (size_t)xrow * 512 + kq_w * 8;
    for (int kb = 0; kb < 16; ++kb) {
        float4 xa = *(const float4*)(xp + kb * 32);
        float4 xb = *(const float4*)(xp + kb * 32 + 4);
        bf16x8 av;
        av[0] = (__bf16)xa.x; av[1] = (__bf16)xa.y;
        av[2] = (__bf16)xa.z; av[3] = (__bf16)xa.w;
        av[4] = (__bf16)xb.x; av[5] = (__bf16)xb.y;
        av[6] = (__bf16)xb.z; av[7] = (__bf16)xb.w;
        *(bf16x8*)(As + ((size_t)kq_w * 64 + mrow) * 8) = av;
        *(bf16x8*)(Bs + ((size_t)wid * 64 + lane) * 8) =
            *(const bf16x8*)(W1b + ((size_t)(kb * 4 + wid) * 64 + lane) * 8);
        __syncthreads();
        bf16x8 af = *(const bf16x8*)(As + ((size_t)quad * 64 + 16 * wid + l15) * 8);
#pragma unroll
        for (int t = 0; t < 4; ++t) {
            bf16x8 bf = *(const bf16x8*)(Bs + ((size_t)quad * 64 + 16 * t + l15) * 8);
            acc[t] = __builtin_amdgcn_mfma_f32_16x16x32_bf16(af, bf, acc[t], 0, 0, 0);
        }
        __syncthreads();
    }
    float asv[4], adv[4];
#pragma unroll
    for (int t = 0; t < 4; ++t) {
        asv[t] = att_s1[16 * t + l15];
        adv[t] = att_d1[16 * t + l15];
    }
#pragma unroll
    for (int t = 0; t < 4; ++t) {
#pragma unroll
        for (int r = 0; r < 4; ++r) {
            int gm = m0 + 16 * wid + quad * 4 + r;
            if (gm < M) H1b[(size_t)gm * 64 + 16 * t + l15] = (__bf16)acc[t][r];
            float ps = acc[t][r] * asv[t];
            float pd = acc[t][r] * adv[t];
            ps += __shfl_xor(ps, 1); ps += __shfl_xor(ps, 2); ps += __shfl_xor(ps, 4);
            pd += __shfl_xor(pd, 1); pd += __shfl_xor(pd, 2); pd += __shfl_xor(pd, 4);
            if (gm < M && (l15 & 7) == 0) {
                int hh = 2 * t + (l15 >> 3);
                a_s1[(size_t)gm * 8 + hh] = ps;
                a_d1[(size_t)gm * 8 + hh] = pd;
            }
        }
    }
}

// ---------------------------------------------------------------------------
// agg1_fused (v7): v3 dataflow (a_src gathered -- faster than R7's recompute)
// with a SINGLE full-depth burst: all <=64 slot values distributed via 8
// shfls, all 8 a_src loads + all 8 H1b-row loads issued back-to-back (16
// outstanding VMEM/lane), one compute phase. Serial memory rounds per node:
// slot -> everything (was slot -> 32-edge burst -> mid loop). Masked groups
// duplicate edge dm1 (L1-served). Exact tail for deg>64. (256,6) = 85-VGPR
// cap, proven spill-free. Epilogue: LDS W2s (deferred barrier), rlane GEMM,
// full 128-B H2b row store with exact f32 a_s2 bits in elems 40/41.
// ---------------------------------------------------------------------------
__global__ __launch_bounds__(256, 6) void agg1_fused(const int* __restrict__ off,
                                                  const int* __restrict__ off_end,
                                                  const int* __restrict__ slot,
                                                  const __bf16* __restrict__ H1b,
                                                  const float* __restrict__ a_src,
                                                  const float* __restrict__ a_dst,
                                                  const float* __restrict__ b1,
                                                  const float* __restrict__ W2,
                                                  const float* __restrict__ att_src2,
                                                  const float* __restrict__ att_dst2,
                                                  __bf16* __restrict__ H2b,
                                                  float* __restrict__ a_d2) {
    __shared__ float W2s[64 * 40];  // 10KB
    int tid = threadIdx.x;
    int wid = tid >> 6, lane = tid & 63;
    for (int i = tid; i < 64 * 40; i += 256) W2s[i] = W2[i];
    // NOTE: __syncthreads() deferred to just before the epilogue (W2s use)
    int d = blockIdx.x * 4 + wid;  // grid exact: 12500*4 = 50000
    int beg = off[d], end = off_end[d];
    int deg = end - beg, dm1 = deg - 1;
    int es = lane >> 3;  // edge sub-index within a group
    int eh = lane & 7;   // head == feature slice (f = eh*8 + q)
    float adst_c = a_dst[(size_t)d * 8 + eh];
    const __bf16* hbase = H1b + eh * 8;
    // round 1: whole adjacency list in one coalesced load
    int sv = slot[beg + ((lane < deg) ? lane : dm1)];
    // distribute all 8 group indices (masked -> dm1 duplicate)
    int sg[8];
#pragma unroll
    for (int g = 0; g < 8; ++g) {
        int idx = g * 8 + es;
        sg[g] = __shfl(sv, (idx < deg) ? idx : dm1);
    }
    // round 2: issue ALL scattered loads back-to-back (16 VMEM in flight)
    float av[8];
#pragma unroll
    for (int g = 0; g < 8; ++g) av[g] = a_src[(size_t)sg[g] * 8 + eh];
    bf16x8 h[8];
#pragma unroll
    for (int g = 0; g < 8; ++g) h[g] = *(const bf16x8*)(hbase + (size_t)sg[g] * 64);
    // compute phase
    float wv[8];
    float den_l = 0.f;
#pragma unroll
    for (int g = 0; g < 8; ++g) {
        float e = av[g] + adst_c;
        e = (e >= 0.f) ? e : NEG_SLOPE * e;
        float w = (g * 8 + es < deg) ? __expf(e) : 0.f;
        wv[g] = w;
        den_l += w;
    }
    float acc[8] = {0.f, 0.f, 0.f, 0.f, 0.f, 0.f, 0.f, 0.f};
#pragma unroll
    for (int g = 0; g < 8; ++g) {
#pragma unroll
        for (int q = 0; q < 8; ++q) acc[q] += wv[g] * (float)h[g][q];
    }
    // exact tail for the (vanishingly rare) deg > 64 nodes
    for (int i = beg + 64; i < end; i += 8) {
        int j = i + es;
        int jj = (j < end) ? j : (end - 1);
        int s = slot[jj];
        float e = a_src[(size_t)s * 8 + eh] + adst_c;
        e = (e >= 0.f) ? e : NEG_SLOPE * e;
        float w = (j < end) ? __expf(e) : 0.f;
        den_l += w;
        bf16x8 hv = *(const bf16x8*)(hbase + (size_t)s * 64);
#pragma unroll
        for (int q = 0; q < 8; ++q) acc[q] += w * (float)hv[q];
    }
    // reduce over the 8 es-lanes (lane bits 3..5); all lanes end up replicated
#pragma unroll
    for (int m = 8; m <= 32; m <<= 1) {
        den_l += __shfl_xor(den_l, m);
#pragma unroll
        for (int q = 0; q < 8; ++q) acc[q] += __shfl_xor(acc[q], m);
    }
    float rden = 1.f / (den_l + 1e-16f);
    float vr[8];
#pragma unroll
    for (int q = 0; q < 8; ++q) {
        float t = acc[q] * rden + b1[eh * 8 + q];
        vr[q] = (t > 0.f) ? t : 0.f;  // relu'd H1R row, feature eh*8+q
    }
    __syncthreads();  // W2s visible (staged at block start, used below)
    // ---- fused layer-2 GEMM + att2: rp[k] via readlane (k compile-time) ----
    int c = lane, cc = (c < 40) ? c : 0;
    float acc2a = 0.f, acc2b = 0.f;
#pragma unroll
    for (int k = 0; k < 64; k += 2) {
        float r0 = rlane(vr[k & 7], k >> 3);
        float r1 = rlane(vr[(k + 1) & 7], (k + 1) >> 3);
        acc2a += r0 * W2s[k * 40 + cc];
        acc2b += r1 * W2s[(k + 1) * 40 + cc];
    }
    float acc2 = acc2a + acc2b;
    float ps = (c < 40) ? acc2 * att_src2[cc] : 0.f;
    float pd = (c < 40) ? acc2 * att_dst2[cc] : 0.f;
#pragma unroll
    for (int mm = 32; mm >= 1; mm >>= 1) {
        ps += __shfl_xor(ps, mm);
        pd += __shfl_xor(pd, mm);
    }
    // full coalesced 128-B row store: 40 bf16 + exact f32 ps bits in elems
    // 40/41 (read back by agg2 as dword0 of the sl=5 slice) + zeros
    unsigned int pbits = __float_as_uint(ps);  // replicated across lanes
    unsigned short st;
    if (c < 40)       st = __builtin_bit_cast(unsigned short, (__bf16)acc2);
    else if (c == 40) st = (unsigned short)(pbits & 0xFFFF);
    else if (c == 41) st = (unsigned short)(pbits >> 16);
    else              st = 0;
    ((unsigned short*)H2b)[(size_t)d * 64 + c] = st;
    if (lane == 0) a_d2[d] = pd;
}

// ---------------------------------------------------------------------------
// agg2 (v7): same single full-depth burst. a_src2 extracted from the row
// itself (dword 0 of the sl=5 slice, bytes 80..83). In-register log-softmax,
// zero LDS. Slices sl>=5 masked before every cross-sl reduction, never stored.
// ---------------------------------------------------------------------------
__global__ __launch_bounds__(256, 6) void agg2(const int* __restrict__ off,
                                            const int* __restrict__ off_end,
                                            const int* __restrict__ slot,
                                            const __bf16* __restrict__ H2b,
                                            const float* __restrict__ a_d2,
                                            const float* __restrict__ b2,
                                            float* __restrict__ out) {
    int tid = threadIdx.x;
    int wid = tid >> 6, lane = tid & 63;
    int d = blockIdx.x * 4 + wid;  // grid exact
    int beg = off[d], end = off_end[d];
    int deg = end - beg, dm1 = deg - 1;
    int es = lane >> 3;  // edge sub-index
    int sl = lane & 7;   // channel slice (f = sl*8 + q, valid f < 40)
    int asl = (lane & 56) | 5;  // lane holding each group's a_src2 dword
    float adst = a_d2[d];
    const __bf16* hbase = H2b + sl * 8;
    bool valid = (sl < 5);
    // round 1: whole adjacency list
    int sv = __builtin_nontemporal_load(slot + beg + ((lane < deg) ? lane : dm1));
    int sg[8];
#pragma unroll
    for (int g = 0; g < 8; ++g) {
        int idx = g * 8 + es;
        sg[g] = __shfl(sv, (idx < deg) ? idx : dm1);
    }
    // round 2: all 8 row loads in flight
    i32x4 rv[8];
#pragma unroll
    for (int g = 0; g < 8; ++g)
        rv[g] = *(const i32x4*)(hbase + (size_t)sg[g] * 64);
    // compute phase (w extracted from the rows themselves)
    float wv[8];
    float den_l = 0.f;
#pragma unroll
    for (int g = 0; g < 8; ++g) {
        float e = __uint_as_float(__shfl(rv[g][0], asl)) + adst;
        e = (e >= 0.f) ? e : NEG_SLOPE * e;
        float w = (g * 8 + es < deg) ? __expf(e) : 0.f;
        wv[g] = w;
        den_l += w;
    }
    float acc[8] = {0.f, 0.f, 0.f, 0.f, 0.f, 0.f, 0.f, 0.f};
#pragma unroll
    for (int g = 0; g < 8; ++g) {
        bf16x8 hv = __builtin_bit_cast(bf16x8, rv[g]);
#pragma unroll
        for (int q = 0; q < 8; ++q) acc[q] += wv[g] * (float)hv[q];
    }
    for (int i = beg + 64; i < end; i += 8) {  // rare deg>64 tail
        int j = i + es;
        int jj = (j < end) ? j : (end - 1);
        int s = slot[jj];
        i32x4 rvt = *(const i32x4*)(hbase + (size_t)s * 64);
        bf16x8 hv = __builtin_bit_cast(bf16x8, rvt);
        float e = __uint_as_float(__shfl(rvt[0], asl)) + adst;
        e = (e >= 0.f) ? e : NEG_SLOPE * e;
        float w = (j < end) ? __expf(e) : 0.f;
        den_l += w;
#pragma unroll
        for (int q = 0; q < 8; ++q) acc[q] += w * (float)hv[q];
    }
    // reduce over es-lanes (bits 3..5); w was replicated across sl, so this
    // sums each edge exactly once per (sl) lane
#pragma unroll
    for (int m = 8; m <= 32; m <<= 1) {
        den_l += __shfl_xor(den_l, m);
#pragma unroll
        for (int q = 0; q < 8; ++q) acc[q] += __shfl_xor(acc[q], m);
    }
    float rden = 1.f / (den_l + 1e-16f);
    float v[8];
    float vm = -3.0e38f;
#pragma unroll
    for (int q = 0; q < 8; ++q) {
        v[q] = acc[q] * rden + b2[valid ? sl * 8 + q : 0];
        vm = fmaxf(vm, v[q]);
    }
    if (!valid) vm = -3.0e38f;
    // channel max over the 5 valid slices: reduce over sl bits (0..2)
#pragma unroll
    for (int m = 1; m <= 4; m <<= 1) vm = fmaxf(vm, __shfl_xor(vm, m));
    float se = 0.f;
#pragma unroll
    for (int q = 0; q < 8; ++q) se += __expf(v[q] - vm);
    if (!valid) se = 0.f;
#pragma unroll
    for (int m = 1; m <= 4; m <<= 1) se += __shfl_xor(se, m);
    float lse = vm + __logf(se);
    if (es == 0 && valid) {
        f32x4 o0 = {v[0] - lse, v[1] - lse, v[2] - lse, v[3] - lse};
        f32x4 o1 = {v[4] - lse, v[5] - lse, v[6] - lse, v[7] - lse};
        __builtin_nontemporal_store(o0, (f32x4*)(out + (size_t)d * 40 + sl * 8));
        __builtin_nontemporal_store(o1, (f32x4*)(out + (size_t)d * 40 + sl * 8 + 4));
    }
}

// ---------------------------------------------------------------------------
extern "C" void kernel_launch(void* const* d_in, const int* in_sizes, int n_in,
                              void* d_out, int out_size, void* d_ws, size_t ws_size,
                              hipStream_t stream) {
    const float* x   = (const float*)d_in[0];
    const int*   ei  = (const int*)d_in[1];
    const float* W1  = (const float*)d_in[2];
    const float* as1 = (const float*)d_in[3];
    const float* ad1 = (const float*)d_in[4];
    const float* b1  = (const float*)d_in[5];
    const float* W2  = (const float*)d_in[6];
    const float* as2 = (const float*)d_in[7];
    const float* ad2 = (const float*)d_in[8];
    const float* b2  = (const float*)d_in[9];
    float* out = (float*)d_out;

    const int N = NNODES;
    const int E = in_sizes[1] / 2;
    const int total = E + N;

    // workspace carve-up
    char* ws = (char*)d_ws;
    size_t o = 0;
    auto alloc = [&](size_t bytes) -> void* {
        void* p = ws + o;
        o = (o + bytes + 255) & ~(size_t)255;
        return p;
    };
    int* bcur    = (int*)alloc((size_t)(NB + 1) * 4);  // +1: gcur at [NB]
    int* off     = (int*)alloc((size_t)N * 4);
    int* off_end = (int*)alloc((size_t)N * 4);
    int* slot    = (int*)alloc((size_t)total * 4);
    int* tmp     = (int*)alloc((size_t)NB * CAP * 4);  // 12.7MB bucket arena
    __bf16* W1b = (__bf16*)alloc((size_t)512 * 64 * 2);
    __bf16* H1b = (__bf16*)alloc((size_t)N * 64 * 2);
    float* a_s1 = (float*)alloc((size_t)N * 8 * 4);
    float* a_d1 = (float*)alloc((size_t)N * 8 * 4);
    __bf16* H2b = (__bf16*)alloc((size_t)N * 64 * 2);  // row: 40 bf16 + a_s2 f32 bits @ elems 40/41
    float* a_d2 = (float*)alloc((size_t)N * 4);
    (void)ws_size; (void)n_in; (void)out_size;

    // prep (W1 pack + bcur init), then binned CSR build (shared by layers)
    prep<<<(512 * 64 + 255) / 256, 256, 0, stream>>>(W1, W1b, bcur);
    bin_scatter<<<(total + CHUNK - 1) / CHUNK, 256, 0, stream>>>(ei, E, N, bcur, tmp);
    csr_finalize<<<NB, 256, 0, stream>>>(bcur, tmp, N, off, off_end, slot);

    // Layer 1 GEMM (+att1 fused: both a_s1 and a_d1)
    gemm1_mfma<<<(N + 63) / 64, 256, 0, stream>>>(x, W1b, as1, ad1, H1b, a_s1, a_d1, N);

    // Layer-1 aggregation + fused layer-2 GEMM/att2 (a_s2 embedded in H2b)
    agg1_fused<<<N / 4, 256, 0, stream>>>(off, off_end, slot, H1b, a_s1, a_d1, b1,
                                          W2, as2, ad2, H2b, a_d2);

    // Layer-2 aggregation + bias + log_softmax
    agg2<<<N / 4, 256, 0, stream>>>(off, off_end, slot, H2b, a_d2, b2, out);
}

// Round 9
// 350.065 us; speedup vs baseline: 1.0126x; 1.0126x over previous
//
#include <hip/hip_runtime.h>
#include <math.h>

#define NNODES 50000
#define NEG_SLOPE 0.2f
#define NB 391       // ceil(50000/128) buckets
#define BW 128       // nodes per bucket
#define CHUNK 4096   // edges per block in bin_scatter
#define CAP 8128     // arena slots per bucket in tmp (mean 4224, sigma ~64)

typedef __bf16 bf16x8 __attribute__((ext_vector_type(8)));
typedef float f32x4 __attribute__((ext_vector_type(4)));
typedef int i32x4 __attribute__((ext_vector_type(4)));

__device__ inline float rlane(float v, int l) {
    return __uint_as_float(__builtin_amdgcn_readlane((int)__float_as_uint(v), l));
}

// ---------------------------------------------------------------------------
// prep: W1 f32 -> bf16 panels [k/8][n][k%8]  +  bcur arena-cursor init.
// ---------------------------------------------------------------------------
__global__ void prep(const float* __restrict__ W1, __bf16* __restrict__ W1b,
                     int* __restrict__ bcur) {
    int i = blockIdx.x * 256 + threadIdx.x;
    if (i < NB) bcur[i] = i * CAP;
    else if (i == NB) bcur[NB] = 0;  // gcur (slot compaction cursor)
    if (i >= 512 * 64) return;
    int k = i >> 6, n = i & 63;
    W1b[((size_t)(k >> 3) * 64 + n) * 8 + (k & 7)] = (__bf16)W1[i];
}

// ---------------------------------------------------------------------------
// bin_scatter: per-block LDS bucket histogram -> one reservation atomic per
// bucket -> packed (dst&127)<<16|src into block-private contiguous tmp runs.
// ---------------------------------------------------------------------------
__global__ __launch_bounds__(256) void bin_scatter(const int* __restrict__ ei,
                                                   int E, int N, int* bcur,
                                                   int* __restrict__ tmp) {
    __shared__ int lcnt[NB];
    __shared__ int lbase[NB];
    int tid = threadIdx.x;
    int base0 = blockIdx.x * CHUNK;
    int lim = min(base0 + CHUNK, E + N);
    for (int i = tid; i < NB; i += 256) lcnt[i] = 0;
    __syncthreads();
    for (int e = base0 + tid; e < lim; e += 256) {
        int d = (e < E) ? ei[E + e] : e - E;  // row 1 = dst; tail = self-loops
        atomicAdd(&lcnt[d >> 7], 1);
    }
    __syncthreads();
    for (int b = tid; b < NB; b += 256) {
        int c = lcnt[b];
        lbase[b] = c ? atomicAdd(&bcur[b], c) : 0;
    }
    __syncthreads();
    for (int i = tid; i < NB; i += 256) lcnt[i] = 0;
    __syncthreads();
    for (int e = base0 + tid; e < lim; e += 256) {
        int s, d;
        if (e < E) { s = ei[e]; d = ei[E + e]; }
        else       { s = d = e - E; }
        int b = d >> 7;
        int p = atomicAdd(&lcnt[b], 1);
        tmp[lbase[b] + p] = ((d & 127) << 16) | s;  // src < 50000 < 2^16
    }
}

// ---------------------------------------------------------------------------
// csr_finalize: one block per bucket; per-node LDS count + scan; block
// reserves m compact slots from gcur; writes off/off_end and scatters slot.
// ---------------------------------------------------------------------------
__global__ __launch_bounds__(256) void csr_finalize(int* __restrict__ bcur,
                                                    const int* __restrict__ tmp,
                                                    int N, int* __restrict__ off,
                                                    int* __restrict__ off_end,
                                                    int* __restrict__ slot) {
    __shared__ int cnt[BW];
    __shared__ int cur[BW];
    __shared__ int cbase_s;
    int b = blockIdx.x, tid = threadIdx.x;
    int base = b * CAP;
    int m = bcur[b] - base;
    if (tid < BW) cnt[tid] = 0;
    __syncthreads();
    for (int i = tid; i < m; i += 256)
        atomicAdd(&cnt[(tmp[base + i] >> 16) & 127], 1);
    __syncthreads();
    if (tid == 0) cbase_s = atomicAdd(&bcur[NB], m);  // compact reservation
    int myv = (tid < BW) ? cnt[tid] : 0;
    for (int o = 1; o < BW; o <<= 1) {
        int u = 0;
        if (tid >= o && tid < BW) u = cnt[tid - o];
        __syncthreads();
        if (tid < BW) cnt[tid] += u;
        __syncthreads();
    }
    if (tid < BW) {
        int ex = cbase_s + cnt[tid] - myv;  // exclusive, compact coords
        cur[tid] = ex;
        int g = b * BW + tid;
        if (g < N) { off[g] = ex; off_end[g] = ex + myv; }
    }
    __syncthreads();
    for (int i = tid; i < m; i += 256) {
        int v = tmp[base + i];
        int k = (v >> 16) & 127;
        int p = atomicAdd(&cur[k], 1);
        slot[p] = v & 0xFFFF;
    }
}

// ---------------------------------------------------------------------------
// gemm1_mfma + fused att1 (R2-proven): H1b = bf16(X) @ bf16(W1); epilogue
// computes BOTH a_src1[n,h] and a_dst1[n,h] from the f32 accumulators.
// D-fragment: col = 16t + l15, row = quad*4 + r. h = 2t + (l15>>3).
// ---------------------------------------------------------------------------
__global__ __launch_bounds__(256) void gemm1_mfma(const float* __restrict__ X,
                                                  const __bf16* __restrict__ W1b,
                                                  const float* __restrict__ att_s1,
                                                  const float* __restrict__ att_d1,
                                                  __bf16* __restrict__ H1b,
                                                  float* __restrict__ a_s1,
                                                  float* __restrict__ a_d1,
                                                  int M) {
    __shared__ __bf16 As[2048];  // [kq 0..3][m 0..63][8]
    __shared__ __bf16 Bs[2048];  // [kq 0..3][n 0..63][8]
    int tid = threadIdx.x, wid = tid >> 6, lane = tid & 63;
    int quad = lane >> 4, l15 = lane & 15;
    int m0 = blockIdx.x * 64;
    f32x4 acc[4] = {{0.f, 0.f, 0.f, 0.f}, {0.f, 0.f, 0.f, 0.f},
                    {0.f, 0.f, 0.f, 0.f}, {0.f, 0.f, 0.f, 0.f}};
    int mrow = tid >> 2;   // 0..63 (staging role)
    int kq_w = tid & 3;    // k-chunk (staging role)
    int xrow = min(m0 + mrow, M - 1);  // clamp: garbage rows never stored
    const float* xp = X + (size_t)xrow * 512 + kq_w * 8;
    for (int kb = 0; kb < 16; ++kb) {
        float4 xa = *(const float4*)(xp + kb * 32);
        float4 xb = *(const float4*)(xp + kb * 32 + 4);
        bf16x8 av;
        av[0] = (__bf16)xa.x; av[1] = (__bf16)xa.y;
        av[2] = (__bf16)xa.z; av[3] = (__bf16)xa.w;
        av[4] = (__bf16)xb.x; av[5] = (__bf16)xb.y;
        av[6] = (__bf16)xb.z; av[7] = (__bf16)xb.w;
        *(bf16x8*)(As + ((size_t)kq_w * 64 + mrow) * 8) = av;
        *(bf16x8*)(Bs + ((size_t)wid * 64 + lane) * 8) =
            *(const bf16x8*)(W1b + ((size_t)(kb * 4 + wid) * 64 + lane) * 8);
        __syncthreads();
        bf16x8 af = *(const bf16x8*)(As + ((size_t)quad * 64 + 16 * wid + l15) * 8);
#pragma unroll
        for (int t = 0; t < 4; ++t) {
            bf16x8 bf = *(const bf16x8*)(Bs + ((size_t)quad * 64 + 16 * t + l15) * 8);
            acc[t] = __builtin_amdgcn_mfma_f32_16x16x32_bf16(af, bf, acc[t], 0, 0, 0);
        }
        __syncthreads();
    }
    float asv[4], adv[4];
#pragma unroll
    for (int t = 0; t < 4; ++t) {
        asv[t] = att_s1[16 * t + l15];
        adv[t] = att_d1[16 * t + l15];
    }
#pragma unroll
    for (int t = 0; t < 4; ++t) {
#pragma unroll
        for (int r = 0; r < 4; ++r) {
            int gm = m0 + 16 * wid + quad * 4 + r;
            if (gm < M) H1b[(size_t)gm * 64 + 16 * t + l15] = (__bf16)acc[t][r];
            float ps = acc[t][r] * asv[t];
            float pd = acc[t][r] * adv[t];
            ps += __shfl_xor(ps, 1); ps += __shfl_xor(ps, 2); ps += __shfl_xor(ps, 4);
            pd += __shfl_xor(pd, 1); pd += __shfl_xor(pd, 2); pd += __shfl_xor(pd, 4);
            if (gm < M && (l15 & 7) == 0) {
                int hh = 2 * t + (l15 >> 3);
                a_s1[(size_t)gm * 8 + hh] = ps;
                a_d1[(size_t)gm * 8 + hh] = pd;
            }
        }
    }
}

// one edge group at compile-time-known batch position; masked when idx >= deg
// (v3-proven interleaved form: load results consumed per-group, no bulk stage)
#define EDGE_GROUP1(IDX, SVAR, WVAR, HVAR, EVAR)                        \
    int SVAR = __shfl(sv, ((IDX) < deg) ? (IDX) : dm1);                 \
    float EVAR = a_src[(size_t)SVAR * 8 + eh] + adst_c;                 \
    EVAR = (EVAR >= 0.f) ? EVAR : NEG_SLOPE * EVAR;                     \
    float WVAR = ((IDX) < deg) ? __expf(EVAR) : 0.f;                    \
    bf16x8 HVAR = *(const bf16x8*)(hbase + (size_t)SVAR * 64);

// ---------------------------------------------------------------------------
// agg1_fused (v8 = v3 with deeper burst + more waves): 6-group prologue
// (48 edges, covers ~99% of Poisson(34) degrees in ONE scattered round) +
// 2-wide mid loop + exact deg>64 tail. __launch_bounds__(256,7): 73-VGPR cap
// (staged peak ~60, no spill) at 7 waves/SIMD. v3's proven dataflow: a_src
// gathered, LDS W2s with deferred barrier, rlane epilogue GEMM, full 128-B
// H2b row store with exact f32 a_s2 bits embedded in elems 40/41.
// ---------------------------------------------------------------------------
__global__ __launch_bounds__(256, 7) void agg1_fused(const int* __restrict__ off,
                                                  const int* __restrict__ off_end,
                                                  const int* __restrict__ slot,
                                                  const __bf16* __restrict__ H1b,
                                                  const float* __restrict__ a_src,
                                                  const float* __restrict__ a_dst,
                                                  const float* __restrict__ b1,
                                                  const float* __restrict__ W2,
                                                  const float* __restrict__ att_src2,
                                                  const float* __restrict__ att_dst2,
                                                  __bf16* __restrict__ H2b,
                                                  float* __restrict__ a_d2) {
    __shared__ float W2s[64 * 40];  // 10KB
    int tid = threadIdx.x;
    int wid = tid >> 6, lane = tid & 63;
    for (int i = tid; i < 64 * 40; i += 256) W2s[i] = W2[i];
    // NOTE: __syncthreads() deferred to just before the epilogue (W2s use)
    int d = blockIdx.x * 4 + wid;  // grid exact: 12500*4 = 50000
    int beg = off[d], end = off_end[d];
    int deg = end - beg, dm1 = deg - 1;
    int es = lane >> 3;  // edge sub-index within the 8-edge group
    int eh = lane & 7;   // head == feature slice (f = eh*8 + q)
    float adst_c = a_dst[(size_t)d * 8 + eh];
    const __bf16* hbase = H1b + eh * 8;
    // one coalesced load grabs the whole adjacency list (deg<=64 common case)
    int sv = slot[beg + ((lane < deg) ? lane : dm1)];
    float acc[8] = {0.f, 0.f, 0.f, 0.f, 0.f, 0.f, 0.f, 0.f};
    float den_l = 0.f;
    {   // prologue: groups 0..5 (idx 0..47) in one burst, masked by deg
        EDGE_GROUP1(es,      s0, w0, h0, e0)
        EDGE_GROUP1(8 + es,  s1, w1, h1, e1)
        EDGE_GROUP1(16 + es, s2, w2, h2, e2)
        EDGE_GROUP1(24 + es, s3, w3, h3, e3)
        EDGE_GROUP1(32 + es, s4, w4, h4, e4)
        EDGE_GROUP1(40 + es, s5, w5, h5, e5)
        den_l = ((w0 + w1) + (w2 + w3)) + (w4 + w5);
#pragma unroll
        for (int q = 0; q < 8; ++q)
            acc[q] = (w0 * (float)h0[q] + w1 * (float)h1[q]) +
                     (w2 * (float)h2[q] + w3 * (float)h3[q]) +
                     (w4 * (float)h4[q] + w5 * (float)h5[q]);
    }
    int dcap = (deg < 64) ? deg : 64;
    for (int b = 48; b < dcap; b += 16) {  // groups 6..7, 2-wide (rare: ~1%)
        EDGE_GROUP1(b + es,     s0, w0, h0, e0)
        EDGE_GROUP1(b + 8 + es, s1, w1, h1, e1)
        den_l += w0 + w1;
#pragma unroll
        for (int q = 0; q < 8; ++q)
            acc[q] += w0 * (float)h0[q] + w1 * (float)h1[q];
    }
    // exact tail for the (vanishingly rare) deg > 64 nodes
    for (int i = beg + 64; i < end; i += 8) {
        int j = i + es;
        int jj = (j < end) ? j : (end - 1);
        int s = slot[jj];
        float e = a_src[(size_t)s * 8 + eh] + adst_c;
        e = (e >= 0.f) ? e : NEG_SLOPE * e;
        float w = (j < end) ? __expf(e) : 0.f;
        den_l += w;
        bf16x8 hv = *(const bf16x8*)(hbase + (size_t)s * 64);
#pragma unroll
        for (int q = 0; q < 8; ++q) acc[q] += w * (float)hv[q];
    }
    // reduce over the 8 es-lanes (lane bits 3..5); all lanes end up replicated
#pragma unroll
    for (int m = 8; m <= 32; m <<= 1) {
        den_l += __shfl_xor(den_l, m);
#pragma unroll
        for (int q = 0; q < 8; ++q) acc[q] += __shfl_xor(acc[q], m);
    }
    float rden = 1.f / (den_l + 1e-16f);
    float vr[8];
#pragma unroll
    for (int q = 0; q < 8; ++q) {
        float t = acc[q] * rden + b1[eh * 8 + q];
        vr[q] = (t > 0.f) ? t : 0.f;  // relu'd H1R row, feature eh*8+q
    }
    __syncthreads();  // W2s visible (staged at block start, used below)
    // ---- fused layer-2 GEMM + att2: rp[k] via readlane (k compile-time) ----
    int c = lane, cc = (c < 40) ? c : 0;
    float acc2a = 0.f, acc2b = 0.f;
#pragma unroll
    for (int k = 0; k < 64; k += 2) {
        float r0 = rlane(vr[k & 7], k >> 3);
        float r1 = rlane(vr[(k + 1) & 7], (k + 1) >> 3);
        acc2a += r0 * W2s[k * 40 + cc];
        acc2b += r1 * W2s[(k + 1) * 40 + cc];
    }
    float acc2 = acc2a + acc2b;
    float ps = (c < 40) ? acc2 * att_src2[cc] : 0.f;
    float pd = (c < 40) ? acc2 * att_dst2[cc] : 0.f;
#pragma unroll
    for (int mm = 32; mm >= 1; mm >>= 1) {
        ps += __shfl_xor(ps, mm);
        pd += __shfl_xor(pd, mm);
    }
    // full coalesced 128-B row store: 40 bf16 + exact f32 ps bits in elems
    // 40/41 (read back by agg2 as dword0 of the sl=5 slice) + zeros
    unsigned int pbits = __float_as_uint(ps);  // replicated across lanes
    unsigned short st;
    if (c < 40)       st = __builtin_bit_cast(unsigned short, (__bf16)acc2);
    else if (c == 40) st = (unsigned short)(pbits & 0xFFFF);
    else if (c == 41) st = (unsigned short)(pbits >> 16);
    else              st = 0;
    ((unsigned short*)H2b)[(size_t)d * 64 + c] = st;
    if (lane == 0) a_d2[d] = pd;
}

// one agg2 edge group; a_src2 extracted from the row itself (dword 0 of the
// sl=5 slice = row bytes 80..83), broadcast to the whole es-group via shfl
#define EDGE_GROUP2(IDX, SVAR, WVAR, HVAR)                              \
    int SVAR = __shfl(sv, ((IDX) < deg) ? (IDX) : dm1);                 \
    i32x4 rv_##HVAR = *(const i32x4*)(hbase + (size_t)SVAR * 64);       \
    bf16x8 HVAR = __builtin_bit_cast(bf16x8, rv_##HVAR);                \
    float e_##HVAR = __uint_as_float(__shfl(rv_##HVAR[0], asl)) + adst; \
    e_##HVAR = (e_##HVAR >= 0.f) ? e_##HVAR : NEG_SLOPE * e_##HVAR;     \
    float WVAR = ((IDX) < deg) ? __expf(e_##HVAR) : 0.f;

// ---------------------------------------------------------------------------
// agg2 (v8): 6-group prologue + 2-wide mid + exact tail, (256,7). a_src2
// rides inside the H2b row. In-register log-softmax, zero LDS. Slices sl>=5
// masked before every cross-sl reduction and never stored.
// ---------------------------------------------------------------------------
__global__ __launch_bounds__(256, 7) void agg2(const int* __restrict__ off,
                                            const int* __restrict__ off_end,
                                            const int* __restrict__ slot,
                                            const __bf16* __restrict__ H2b,
                                            const float* __restrict__ a_d2,
                                            const float* __restrict__ b2,
                                            float* __restrict__ out) {
    int tid = threadIdx.x;
    int wid = tid >> 6, lane = tid & 63;
    int d = blockIdx.x * 4 + wid;  // grid exact
    int beg = off[d], end = off_end[d];
    int deg = end - beg, dm1 = deg - 1;
    int es = lane >> 3;  // edge sub-index
    int sl = lane & 7;   // channel slice (f = sl*8 + q, valid f < 40)
    int asl = (lane & 56) | 5;  // lane holding this group's a_src2 dword
    float adst = a_d2[d];
    const __bf16* hbase = H2b + sl * 8;
    bool valid = (sl < 5);
    int sv = __builtin_nontemporal_load(slot + beg + ((lane < deg) ? lane : dm1));
    float acc[8] = {0.f, 0.f, 0.f, 0.f, 0.f, 0.f, 0.f, 0.f};
    float den_l = 0.f;
    {   // prologue burst: groups 0..5
        EDGE_GROUP2(es,      s0, w0, h0)
        EDGE_GROUP2(8 + es,  s1, w1, h1)
        EDGE_GROUP2(16 + es, s2, w2, h2)
        EDGE_GROUP2(24 + es, s3, w3, h3)
        EDGE_GROUP2(32 + es, s4, w4, h4)
        EDGE_GROUP2(40 + es, s5, w5, h5)
        den_l = ((w0 + w1) + (w2 + w3)) + (w4 + w5);
#pragma unroll
        for (int q = 0; q < 8; ++q)
            acc[q] = (w0 * (float)h0[q] + w1 * (float)h1[q]) +
                     (w2 * (float)h2[q] + w3 * (float)h3[q]) +
                     (w4 * (float)h4[q] + w5 * (float)h5[q]);
    }
    int dcap = (deg < 64) ? deg : 64;
    for (int b = 48; b < dcap; b += 16) {  // 2-wide (rare: ~1%)
        EDGE_GROUP2(b + es,     s0, w0, h0)
        EDGE_GROUP2(b + 8 + es, s1, w1, h1)
        den_l += w0 + w1;
#pragma unroll
        for (int q = 0; q < 8; ++q)
            acc[q] += w0 * (float)h0[q] + w1 * (float)h1[q];
    }
    for (int i = beg + 64; i < end; i += 8) {  // rare deg>64 tail
        int j = i + es;
        int jj = (j < end) ? j : (end - 1);
        int s = slot[jj];
        i32x4 rv = *(const i32x4*)(hbase + (size_t)s * 64);
        bf16x8 hv = __builtin_bit_cast(bf16x8, rv);
        float e = __uint_as_float(__shfl(rv[0], asl)) + adst;
        e = (e >= 0.f) ? e : NEG_SLOPE * e;
        float w = (j < end) ? __expf(e) : 0.f;
        den_l += w;
#pragma unroll
        for (int q = 0; q < 8; ++q) acc[q] += w * (float)hv[q];
    }
    // reduce over es-lanes (bits 3..5); w was replicated across sl, so this
    // sums each edge exactly once per (sl) lane
#pragma unroll
    for (int m = 8; m <= 32; m <<= 1) {
        den_l += __shfl_xor(den_l, m);
#pragma unroll
        for (int q = 0; q < 8; ++q) acc[q] += __shfl_xor(acc[q], m);
    }
    float rden = 1.f / (den_l + 1e-16f);
    float v[8];
    float vm = -3.0e38f;
#pragma unroll
    for (int q = 0; q < 8; ++q) {
        v[q] = acc[q] * rden + b2[valid ? sl * 8 + q : 0];
        vm = fmaxf(vm, v[q]);
    }
    if (!valid) vm = -3.0e38f;
    // channel max over the 5 valid slices: reduce over sl bits (0..2)
#pragma unroll
    for (int m = 1; m <= 4; m <<= 1) vm = fmaxf(vm, __shfl_xor(vm, m));
    float se = 0.f;
#pragma unroll
    for (int q = 0; q < 8; ++q) se += __expf(v[q] - vm);
    if (!valid) se = 0.f;
#pragma unroll
    for (int m = 1; m <= 4; m <<= 1) se += __shfl_xor(se, m);
    float lse = vm + __logf(se);
    if (es == 0 && valid) {
        f32x4 o0 = {v[0] - lse, v[1] - lse, v[2] - lse, v[3] - lse};
        f32x4 o1 = {v[4] - lse, v[5] - lse, v[6] - lse, v[7] - lse};
        __builtin_nontemporal_store(o0, (f32x4*)(out + (size_t)d * 40 + sl * 8));
        __builtin_nontemporal_store(o1, (f32x4*)(out + (size_t)d * 40 + sl * 8 + 4));
    }
}

// ---------------------------------------------------------------------------
extern "C" void kernel_launch(void* const* d_in, const int* in_sizes, int n_in,
                              void* d_out, int out_size, void* d_ws, size_t ws_size,
                              hipStream_t stream) {
    const float* x   = (const float*)d_in[0];
    const int*   ei  = (const int*)d_in[1];
    const float* W1  = (const float*)d_in[2];
    const float* as1 = (const float*)d_in[3];
    const float* ad1 = (const float*)d_in[4];
    const float* b1  = (const float*)d_in[5];
    const float* W2  = (const float*)d_in[6];
    const float* as2 = (const float*)d_in[7];
    const float* ad2 = (const float*)d_in[8];
    const float* b2  = (const float*)d_in[9];
    float* out = (float*)d_out;

    const int N = NNODES;
    const int E = in_sizes[1] / 2;
    const int total = E + N;

    // workspace carve-up
    char* ws = (char*)d_ws;
    size_t o = 0;
    auto alloc = [&](size_t bytes) -> void* {
        void* p = ws + o;
        o = (o + bytes + 255) & ~(size_t)255;
        return p;
    };
    int* bcur    = (int*)alloc((size_t)(NB + 1) * 4);  // +1: gcur at [NB]
    int* off     = (int*)alloc((size_t)N * 4);
    int* off_end = (int*)alloc((size_t)N * 4);
    int* slot    = (int*)alloc((size_t)total * 4);
    int* tmp     = (int*)alloc((size_t)NB * CAP * 4);  // 12.7MB bucket arena
    __bf16* W1b = (__bf16*)alloc((size_t)512 * 64 * 2);
    __bf16* H1b = (__bf16*)alloc((size_t)N * 64 * 2);
    float* a_s1 = (float*)alloc((size_t)N * 8 * 4);
    float* a_d1 = (float*)alloc((size_t)N * 8 * 4);
    __bf16* H2b = (__bf16*)alloc((size_t)N * 64 * 2);  // row: 40 bf16 + a_s2 f32 bits @ elems 40/41
    float* a_d2 = (float*)alloc((size_t)N * 4);
    (void)ws_size; (void)n_in; (void)out_size;

    // prep (W1 pack + bcur init), then binned CSR build (shared by layers)
    prep<<<(512 * 64 + 255) / 256, 256, 0, stream>>>(W1, W1b, bcur);
    bin_scatter<<<(total + CHUNK - 1) / CHUNK, 256, 0, stream>>>(ei, E, N, bcur, tmp);
    csr_finalize<<<NB, 256, 0, stream>>>(bcur, tmp, N, off, off_end, slot);

    // Layer 1 GEMM (+att1 fused: both a_s1 and a_d1)
    gemm1_mfma<<<(N + 63) / 64, 256, 0, stream>>>(x, W1b, as1, ad1, H1b, a_s1, a_d1, N);

    // Layer-1 aggregation + fused layer-2 GEMM/att2 (a_s2 embedded in H2b)
    agg1_fused<<<N / 4, 256, 0, stream>>>(off, off_end, slot, H1b, a_s1, a_d1, b1,
                                          W2, as2, ad2, H2b, a_d2);

    // Layer-2 aggregation + bias + log_softmax
    agg2<<<N / 4, 256, 0, stream>>>(off, off_end, slot, H2b, a_d2, b2, out);
}

// Round 10
// 316.944 us; speedup vs baseline: 1.1184x; 1.1045x over previous
//
#include <hip/hip_runtime.h>
#include <math.h>

#define NNODES 50000
#define NEG_SLOPE 0.2f
#define NB 391       // ceil(50000/128) buckets
#define BW 128       // nodes per bucket
#define CHUNK 4096   // edges per block in bin_scatter role
#define CAP 8128     // arena slots per bucket in tmp (mean 4224, sigma ~64)

typedef __bf16 bf16x8 __attribute__((ext_vector_type(8)));
typedef float f32x4 __attribute__((ext_vector_type(4)));
typedef int i32x4 __attribute__((ext_vector_type(4)));

__device__ inline float rlane(float v, int l) {
    return __uint_as_float(__builtin_amdgcn_readlane((int)__float_as_uint(v), l));
}

// ---------------------------------------------------------------------------
// prep: W1 f32 -> bf16 panels [k/8][n][k%8]  +  bcur arena-cursor init.
// ---------------------------------------------------------------------------
__global__ void prep(const float* __restrict__ W1, __bf16* __restrict__ W1b,
                     int* __restrict__ bcur) {
    int i = blockIdx.x * 256 + threadIdx.x;
    if (i < NB) bcur[i] = i * CAP;
    else if (i == NB) bcur[NB] = 0;  // gcur (slot compaction cursor)
    if (i >= 512 * 64) return;
    int k = i >> 6, n = i & 63;
    W1b[((size_t)(k >> 3) * 64 + n) * 8 + (k & 7)] = (__bf16)W1[i];
}

// ---------------------------------------------------------------------------
// gemm1_bin: MERGED [gemm1 || bin_scatter].  Blocks < GB run the layer-1
// MFMA GEMM (+fused att1); blocks >= GB run the binned CSR scatter.  The two
// halves touch disjoint data, so they overlap on the machine (1185 blocks,
// ~all co-resident) -> serialized cost g+bs collapses to ~max(g,bs).
// bin half is now SINGLE-PASS over ei: the chunk is cached in LDS as
// (b<<23)|(d&127)<<16|s  (b=d>>7<=390: 9b, d&127: 7b, s<50000: 16b = 32b),
// deleting the 6.6 MB second read of ei.  LDS overlaid: gemm uses As/Bs
// (8 KB), bin uses lcnt/lbase/ev (19.2 KB); union = 19.2 KB.
// ---------------------------------------------------------------------------
__global__ __launch_bounds__(256) void gemm1_bin(
        const float* __restrict__ X, const __bf16* __restrict__ W1b,
        const float* __restrict__ att_s1, const float* __restrict__ att_d1,
        __bf16* __restrict__ H1b, float* __restrict__ a_s1,
        float* __restrict__ a_d1, int M,
        const int* __restrict__ ei, int E, int* bcur, int* __restrict__ tmp,
        int GB) {
    __shared__ __attribute__((aligned(16))) char smem[19584];
    int tid = threadIdx.x;
    if ((int)blockIdx.x < GB) {
        // ---------------- gemm1 role (proven R2 body) ----------------
        __bf16* As = (__bf16*)smem;          // 4 KB [kq][m][8]
        __bf16* Bs = (__bf16*)(smem + 4096); // 4 KB [kq][n][8]
        int wid = tid >> 6, lane = tid & 63;
        int quad = lane >> 4, l15 = lane & 15;
        int m0 = blockIdx.x * 64;
        f32x4 acc[4] = {{0.f, 0.f, 0.f, 0.f}, {0.f, 0.f, 0.f, 0.f},
                        {0.f, 0.f, 0.f, 0.f}, {0.f, 0.f, 0.f, 0.f}};
        int mrow = tid >> 2;   // 0..63 (staging role)
        int kq_w = tid & 3;    // k-chunk (staging role)
        int xrow = min(m0 + mrow, M - 1);  // clamp: garbage rows never stored
        const float* xp = X + (size_t)xrow * 512 + kq_w * 8;
        for (int kb = 0; kb < 16; ++kb) {
            float4 xa = *(const float4*)(xp + kb * 32);
            float4 xb = *(const float4*)(xp + kb * 32 + 4);
            bf16x8 av;
            av[0] = (__bf16)xa.x; av[1] = (__bf16)xa.y;
            av[2] = (__bf16)xa.z; av[3] = (__bf16)xa.w;
            av[4] = (__bf16)xb.x; av[5] = (__bf16)xb.y;
            av[6] = (__bf16)xb.z; av[7] = (__bf16)xb.w;
            *(bf16x8*)(As + ((size_t)kq_w * 64 + mrow) * 8) = av;
            *(bf16x8*)(Bs + ((size_t)wid * 64 + lane) * 8) =
                *(const bf16x8*)(W1b + ((size_t)(kb * 4 + wid) * 64 + lane) * 8);
            __syncthreads();
            bf16x8 af = *(const bf16x8*)(As + ((size_t)quad * 64 + 16 * wid + l15) * 8);
#pragma unroll
            for (int t = 0; t < 4; ++t) {
                bf16x8 bf = *(const bf16x8*)(Bs + ((size_t)quad * 64 + 16 * t + l15) * 8);
                acc[t] = __builtin_amdgcn_mfma_f32_16x16x32_bf16(af, bf, acc[t], 0, 0, 0);
            }
            __syncthreads();
        }
        float asv[4], adv[4];
#pragma unroll
        for (int t = 0; t < 4; ++t) {
            asv[t] = att_s1[16 * t + l15];
            adv[t] = att_d1[16 * t + l15];
        }
#pragma unroll
        for (int t = 0; t < 4; ++t) {
#pragma unroll
            for (int r = 0; r < 4; ++r) {
                int gm = m0 + 16 * wid + quad * 4 + r;
                if (gm < M) H1b[(size_t)gm * 64 + 16 * t + l15] = (__bf16)acc[t][r];
                float ps = acc[t][r] * asv[t];
                float pd = acc[t][r] * adv[t];
                ps += __shfl_xor(ps, 1); ps += __shfl_xor(ps, 2); ps += __shfl_xor(ps, 4);
                pd += __shfl_xor(pd, 1); pd += __shfl_xor(pd, 2); pd += __shfl_xor(pd, 4);
                if (gm < M && (l15 & 7) == 0) {
                    int hh = 2 * t + (l15 >> 3);
                    a_s1[(size_t)gm * 8 + hh] = ps;
                    a_d1[(size_t)gm * 8 + hh] = pd;
                }
            }
        }
    } else {
        // ---------------- bin_scatter role (single-pass over ei) -----------
        int* lcnt  = (int*)smem;                  // NB ints
        int* lbase = (int*)(smem + 1564);         // NB ints
        int* ev    = (int*)(smem + 3200);         // CHUNK ints (16 KB)
        int bid = blockIdx.x - GB;
        int base0 = bid * CHUNK;
        int total = E + NNODES;
        int lim = min(base0 + CHUNK, total);
        for (int i = tid; i < NB; i += 256) lcnt[i] = 0;
        __syncthreads();
        for (int e = base0 + tid; e < lim; e += 256) {
            int s, d;
            if (e < E) { s = ei[e]; d = ei[E + e]; }
            else       { s = d = e - E; }  // self-loop tail
            int b = d >> 7;
            ev[e - base0] = (b << 23) | ((d & 127) << 16) | s;
            atomicAdd(&lcnt[b], 1);
        }
        __syncthreads();
        for (int b = tid; b < NB; b += 256) {
            int c = lcnt[b];
            lbase[b] = c ? atomicAdd(&bcur[b], c) : 0;
        }
        __syncthreads();
        for (int i = tid; i < NB; i += 256) lcnt[i] = 0;
        __syncthreads();
        for (int e = base0 + tid; e < lim; e += 256) {
            int v = ev[e - base0];
            int b = (int)((unsigned)v >> 23);
            int p = atomicAdd(&lcnt[b], 1);
            tmp[lbase[b] + p] = v & 0x7FFFFF;  // (d&127)<<16 | s
        }
    }
}

// ---------------------------------------------------------------------------
// csr_finalize: one block per bucket; per-node LDS count + scan; block
// reserves m compact slots from gcur; writes off/off_end and scatters slot.
// ---------------------------------------------------------------------------
__global__ __launch_bounds__(256) void csr_finalize(int* __restrict__ bcur,
                                                    const int* __restrict__ tmp,
                                                    int N, int* __restrict__ off,
                                                    int* __restrict__ off_end,
                                                    int* __restrict__ slot) {
    __shared__ int cnt[BW];
    __shared__ int cur[BW];
    __shared__ int cbase_s;
    int b = blockIdx.x, tid = threadIdx.x;
    int base = b * CAP;
    int m = bcur[b] - base;
    if (tid < BW) cnt[tid] = 0;
    __syncthreads();
    for (int i = tid; i < m; i += 256)
        atomicAdd(&cnt[(tmp[base + i] >> 16) & 127], 1);
    __syncthreads();
    if (tid == 0) cbase_s = atomicAdd(&bcur[NB], m);  // compact reservation
    int myv = (tid < BW) ? cnt[tid] : 0;
    for (int o = 1; o < BW; o <<= 1) {
        int u = 0;
        if (tid >= o && tid < BW) u = cnt[tid - o];
        __syncthreads();
        if (tid < BW) cnt[tid] += u;
        __syncthreads();
    }
    if (tid < BW) {
        int ex = cbase_s + cnt[tid] - myv;  // exclusive, compact coords
        cur[tid] = ex;
        int g = b * BW + tid;
        if (g < N) { off[g] = ex; off_end[g] = ex + myv; }
    }
    __syncthreads();
    for (int i = tid; i < m; i += 256) {
        int v = tmp[base + i];
        int k = (v >> 16) & 127;
        int p = atomicAdd(&cur[k], 1);
        slot[p] = v & 0xFFFF;
    }
}

// one edge group at compile-time-known batch position; masked when idx >= deg
#define EDGE_GROUP1(IDX, SVAR, WVAR, HVAR, EVAR)                        \
    int SVAR = __shfl(sv, ((IDX) < deg) ? (IDX) : dm1);                 \
    float EVAR = a_src[(size_t)SVAR * 8 + eh] + adst_c;                 \
    EVAR = (EVAR >= 0.f) ? EVAR : NEG_SLOPE * EVAR;                     \
    float WVAR = ((IDX) < deg) ? __expf(EVAR) : 0.f;                    \
    bf16x8 HVAR = *(const bf16x8*)(hbase + (size_t)SVAR * 64);

// ---------------------------------------------------------------------------
// agg1_fused (v9 = exact v3 champion structure, 71.5 us): 4-group prologue +
// 2-wide mid + exact deg>64 tail at (256,8).  LDS W2s with deferred barrier.
// Only delta vs R2: epilogue embeds exact f32 a_s2 bits in H2b elems 40/41
// (feeds agg2's gather-free path; ran clean in R7/R9).
// ---------------------------------------------------------------------------
__global__ __launch_bounds__(256, 8) void agg1_fused(const int* __restrict__ off,
                                                  const int* __restrict__ off_end,
                                                  const int* __restrict__ slot,
                                                  const __bf16* __restrict__ H1b,
                                                  const float* __restrict__ a_src,
                                                  const float* __restrict__ a_dst,
                                                  const float* __restrict__ b1,
                                                  const float* __restrict__ W2,
                                                  const float* __restrict__ att_src2,
                                                  const float* __restrict__ att_dst2,
                                                  __bf16* __restrict__ H2b,
                                                  float* __restrict__ a_d2) {
    __shared__ float W2s[64 * 40];  // 10KB
    int tid = threadIdx.x;
    int wid = tid >> 6, lane = tid & 63;
    for (int i = tid; i < 64 * 40; i += 256) W2s[i] = W2[i];
    // NOTE: __syncthreads() deferred to just before the epilogue (W2s use)
    int d = blockIdx.x * 4 + wid;  // grid exact: 12500*4 = 50000
    int beg = off[d], end = off_end[d];
    int deg = end - beg, dm1 = deg - 1;
    int es = lane >> 3;  // edge sub-index within the 8-edge group
    int eh = lane & 7;   // head == feature slice (f = eh*8 + q)
    float adst_c = a_dst[(size_t)d * 8 + eh];
    const __bf16* hbase = H1b + eh * 8;
    // one coalesced load grabs the whole adjacency list (deg<=64 common case)
    int sv = slot[beg + ((lane < deg) ? lane : dm1)];
    float acc[8] = {0.f, 0.f, 0.f, 0.f, 0.f, 0.f, 0.f, 0.f};
    float den_l = 0.f;
    {   // prologue: groups 0..3 (idx 0..31) in one burst, masked by deg
        EDGE_GROUP1(es,      s0, w0, h0, e0)
        EDGE_GROUP1(8 + es,  s1, w1, h1, e1)
        EDGE_GROUP1(16 + es, s2, w2, h2, e2)
        EDGE_GROUP1(24 + es, s3, w3, h3, e3)
        den_l = ((w0 + w1) + (w2 + w3));
#pragma unroll
        for (int q = 0; q < 8; ++q)
            acc[q] = w0 * (float)h0[q] + w1 * (float)h1[q] +
                     w2 * (float)h2[q] + w3 * (float)h3[q];
    }
    int dcap = (deg < 64) ? deg : 64;
    for (int b = 32; b < dcap; b += 16) {  // groups 4..7, 2-wide
        EDGE_GROUP1(b + es,     s0, w0, h0, e0)
        EDGE_GROUP1(b + 8 + es, s1, w1, h1, e1)
        den_l += w0 + w1;
#pragma unroll
        for (int q = 0; q < 8; ++q)
            acc[q] += w0 * (float)h0[q] + w1 * (float)h1[q];
    }
    // exact tail for the (vanishingly rare) deg > 64 nodes
    for (int i = beg + 64; i < end; i += 8) {
        int j = i + es;
        int jj = (j < end) ? j : (end - 1);
        int s = slot[jj];
        float e = a_src[(size_t)s * 8 + eh] + adst_c;
        e = (e >= 0.f) ? e : NEG_SLOPE * e;
        float w = (j < end) ? __expf(e) : 0.f;
        den_l += w;
        bf16x8 hv = *(const bf16x8*)(hbase + (size_t)s * 64);
#pragma unroll
        for (int q = 0; q < 8; ++q) acc[q] += w * (float)hv[q];
    }
    // reduce over the 8 es-lanes (lane bits 3..5); all lanes end up replicated
#pragma unroll
    for (int m = 8; m <= 32; m <<= 1) {
        den_l += __shfl_xor(den_l, m);
#pragma unroll
        for (int q = 0; q < 8; ++q) acc[q] += __shfl_xor(acc[q], m);
    }
    float rden = 1.f / (den_l + 1e-16f);
    float vr[8];
#pragma unroll
    for (int q = 0; q < 8; ++q) {
        float t = acc[q] * rden + b1[eh * 8 + q];
        vr[q] = (t > 0.f) ? t : 0.f;  // relu'd H1R row, feature eh*8+q
    }
    __syncthreads();  // W2s visible (staged at block start, used below)
    // ---- fused layer-2 GEMM + att2: rp[k] via readlane (k compile-time) ----
    int c = lane, cc = (c < 40) ? c : 0;
    float acc2a = 0.f, acc2b = 0.f;
#pragma unroll
    for (int k = 0; k < 64; k += 2) {
        float r0 = rlane(vr[k & 7], k >> 3);
        float r1 = rlane(vr[(k + 1) & 7], (k + 1) >> 3);
        acc2a += r0 * W2s[k * 40 + cc];
        acc2b += r1 * W2s[(k + 1) * 40 + cc];
    }
    float acc2 = acc2a + acc2b;
    float ps = (c < 40) ? acc2 * att_src2[cc] : 0.f;
    float pd = (c < 40) ? acc2 * att_dst2[cc] : 0.f;
#pragma unroll
    for (int mm = 32; mm >= 1; mm >>= 1) {
        ps += __shfl_xor(ps, mm);
        pd += __shfl_xor(pd, mm);
    }
    // full coalesced 128-B row store: 40 bf16 + exact f32 ps bits in elems
    // 40/41 (read back by agg2 as dword0 of the sl=5 slice) + zeros
    unsigned int pbits = __float_as_uint(ps);  // replicated across lanes
    unsigned short st;
    if (c < 40)       st = __builtin_bit_cast(unsigned short, (__bf16)acc2);
    else if (c == 40) st = (unsigned short)(pbits & 0xFFFF);
    else if (c == 41) st = (unsigned short)(pbits >> 16);
    else              st = 0;
    ((unsigned short*)H2b)[(size_t)d * 64 + c] = st;
    if (lane == 0) a_d2[d] = pd;
}

// one agg2 edge group; a_src2 extracted from the row itself (dword 0 of the
// sl=5 slice = row bytes 80..83), broadcast to the whole es-group via shfl
#define EDGE_GROUP2(IDX, SVAR, WVAR, HVAR)                              \
    int SVAR = __shfl(sv, ((IDX) < deg) ? (IDX) : dm1);                 \
    i32x4 rv_##HVAR = *(const i32x4*)(hbase + (size_t)SVAR * 64);       \
    bf16x8 HVAR = __builtin_bit_cast(bf16x8, rv_##HVAR);                \
    float e_##HVAR = __uint_as_float(__shfl(rv_##HVAR[0], asl)) + adst; \
    e_##HVAR = (e_##HVAR >= 0.f) ? e_##HVAR : NEG_SLOPE * e_##HVAR;     \
    float WVAR = ((IDX) < deg) ? __expf(e_##HVAR) : 0.f;

// ---------------------------------------------------------------------------
// agg2 (proven R7 form, (256,8)): 4-group prologue + 4-wide mid + exact tail;
// a_src2 rides inside the H2b row.  In-register log-softmax, zero LDS.
// Slices sl>=5 masked before every cross-sl reduction and never stored.
// ---------------------------------------------------------------------------
__global__ __launch_bounds__(256, 8) void agg2(const int* __restrict__ off,
                                            const int* __restrict__ off_end,
                                            const int* __restrict__ slot,
                                            const __bf16* __restrict__ H2b,
                                            const float* __restrict__ a_d2,
                                            const float* __restrict__ b2,
                                            float* __restrict__ out) {
    int tid = threadIdx.x;
    int wid = tid >> 6, lane = tid & 63;
    int d = blockIdx.x * 4 + wid;  // grid exact
    int beg = off[d], end = off_end[d];
    int deg = end - beg, dm1 = deg - 1;
    int es = lane >> 3;  // edge sub-index
    int sl = lane & 7;   // channel slice (f = sl*8 + q, valid f < 40)
    int asl = (lane & 56) | 5;  // lane holding this group's a_src2 dword
    float adst = a_d2[d];
    const __bf16* hbase = H2b + sl * 8;
    bool valid = (sl < 5);
    int sv = __builtin_nontemporal_load(slot + beg + ((lane < deg) ? lane : dm1));
    float acc[8] = {0.f, 0.f, 0.f, 0.f, 0.f, 0.f, 0.f, 0.f};
    float den_l = 0.f;
    {   // prologue burst: groups 0..3
        EDGE_GROUP2(es,      s0, w0, h0)
        EDGE_GROUP2(8 + es,  s1, w1, h1)
        EDGE_GROUP2(16 + es, s2, w2, h2)
        EDGE_GROUP2(24 + es, s3, w3, h3)
        den_l = ((w0 + w1) + (w2 + w3));
#pragma unroll
        for (int q = 0; q < 8; ++q)
            acc[q] = w0 * (float)h0[q] + w1 * (float)h1[q] +
                     w2 * (float)h2[q] + w3 * (float)h3[q];
    }
    int dcap = (deg < 64) ? deg : 64;
    for (int b = 32; b < dcap; b += 32) {  // 4-wide burst
        EDGE_GROUP2(b + es,      s0, w0, h0)
        EDGE_GROUP2(b + 8 + es,  s1, w1, h1)
        EDGE_GROUP2(b + 16 + es, s2, w2, h2)
        EDGE_GROUP2(b + 24 + es, s3, w3, h3)
        den_l += ((w0 + w1) + (w2 + w3));
#pragma unroll
        for (int q = 0; q < 8; ++q)
            acc[q] += w0 * (float)h0[q] + w1 * (float)h1[q] +
                      w2 * (float)h2[q] + w3 * (float)h3[q];
    }
    for (int i = beg + 64; i < end; i += 8) {  // rare deg>64 tail
        int j = i + es;
        int jj = (j < end) ? j : (end - 1);
        int s = slot[jj];
        i32x4 rv = *(const i32x4*)(hbase + (size_t)s * 64);
        bf16x8 hv = __builtin_bit_cast(bf16x8, rv);
        float e = __uint_as_float(__shfl(rv[0], asl)) + adst;
        e = (e >= 0.f) ? e : NEG_SLOPE * e;
        float w = (j < end) ? __expf(e) : 0.f;
        den_l += w;
#pragma unroll
        for (int q = 0; q < 8; ++q) acc[q] += w * (float)hv[q];
    }
    // reduce over es-lanes (bits 3..5); w was replicated across sl, so this
    // sums each edge exactly once per (sl) lane
#pragma unroll
    for (int m = 8; m <= 32; m <<= 1) {
        den_l += __shfl_xor(den_l, m);
#pragma unroll
        for (int q = 0; q < 8; ++q) acc[q] += __shfl_xor(acc[q], m);
    }
    float rden = 1.f / (den_l + 1e-16f);
    float v[8];
    float vm = -3.0e38f;
#pragma unroll
    for (int q = 0; q < 8; ++q) {
        v[q] = acc[q] * rden + b2[valid ? sl * 8 + q : 0];
        vm = fmaxf(vm, v[q]);
    }
    if (!valid) vm = -3.0e38f;
    // channel max over the 5 valid slices: reduce over sl bits (0..2)
#pragma unroll
    for (int m = 1; m <= 4; m <<= 1) vm = fmaxf(vm, __shfl_xor(vm, m));
    float se = 0.f;
#pragma unroll
    for (int q = 0; q < 8; ++q) se += __expf(v[q] - vm);
    if (!valid) se = 0.f;
#pragma unroll
    for (int m = 1; m <= 4; m <<= 1) se += __shfl_xor(se, m);
    float lse = vm + __logf(se);
    if (es == 0 && valid) {
        f32x4 o0 = {v[0] - lse, v[1] - lse, v[2] - lse, v[3] - lse};
        f32x4 o1 = {v[4] - lse, v[5] - lse, v[6] - lse, v[7] - lse};
        __builtin_nontemporal_store(o0, (f32x4*)(out + (size_t)d * 40 + sl * 8));
        __builtin_nontemporal_store(o1, (f32x4*)(out + (size_t)d * 40 + sl * 8 + 4));
    }
}

// ---------------------------------------------------------------------------
extern "C" void kernel_launch(void* const* d_in, const int* in_sizes, int n_in,
                              void* d_out, int out_size, void* d_ws, size_t ws_size,
                              hipStream_t stream) {
    const float* x   = (const float*)d_in[0];
    const int*   ei  = (const int*)d_in[1];
    const float* W1  = (const float*)d_in[2];
    const float* as1 = (const float*)d_in[3];
    const float* ad1 = (const float*)d_in[4];
    const float* b1  = (const float*)d_in[5];
    const float* W2  = (const float*)d_in[6];
    const float* as2 = (const float*)d_in[7];
    const float* ad2 = (const float*)d_in[8];
    const float* b2  = (const float*)d_in[9];
    float* out = (float*)d_out;

    const int N = NNODES;
    const int E = in_sizes[1] / 2;
    const int total = E + N;

    // workspace carve-up
    char* ws = (char*)d_ws;
    size_t o = 0;
    auto alloc = [&](size_t bytes) -> void* {
        void* p = ws + o;
        o = (o + bytes + 255) & ~(size_t)255;
        return p;
    };
    int* bcur    = (int*)alloc((size_t)(NB + 1) * 4);  // +1: gcur at [NB]
    int* off     = (int*)alloc((size_t)N * 4);
    int* off_end = (int*)alloc((size_t)N * 4);
    int* slot    = (int*)alloc((size_t)total * 4);
    int* tmp     = (int*)alloc((size_t)NB * CAP * 4);  // 12.7MB bucket arena
    __bf16* W1b = (__bf16*)alloc((size_t)512 * 64 * 2);
    __bf16* H1b = (__bf16*)alloc((size_t)N * 64 * 2);
    float* a_s1 = (float*)alloc((size_t)N * 8 * 4);
    float* a_d1 = (float*)alloc((size_t)N * 8 * 4);
    __bf16* H2b = (__bf16*)alloc((size_t)N * 64 * 2);  // row: 40 bf16 + a_s2 f32 bits @ elems 40/41
    float* a_d2 = (float*)alloc((size_t)N * 4);
    (void)ws_size; (void)n_in; (void)out_size;

    // prep (W1 pack + bcur init)
    prep<<<(512 * 64 + 255) / 256, 256, 0, stream>>>(W1, W1b, bcur);

    // MERGED: layer-1 GEMM (+att1) || binned edge scatter  (independent work)
    const int GB = (N + 63) / 64;                    // 782 gemm blocks
    const int SB = (total + CHUNK - 1) / CHUNK;      // ~403 scatter blocks
    gemm1_bin<<<GB + SB, 256, 0, stream>>>(x, W1b, as1, ad1, H1b, a_s1, a_d1, N,
                                           ei, E, bcur, tmp, GB);

    // CSR finalize (needs scatter done)
    csr_finalize<<<NB, 256, 0, stream>>>(bcur, tmp, N, off, off_end, slot);

    // Layer-1 aggregation + fused layer-2 GEMM/att2 (a_s2 embedded in H2b)
    agg1_fused<<<N / 4, 256, 0, stream>>>(off, off_end, slot, H1b, a_s1, a_d1, b1,
                                          W2, as2, ad2, H2b, a_d2);

    // Layer-2 aggregation + bias + log_softmax
    agg2<<<N / 4, 256, 0, stream>>>(off, off_end, slot, H2b, a_d2, b2, out);
}